// Round 14
// baseline (26.678 us; speedup 1.0000x reference)
//
#include <hip/hip_runtime.h>
#include <math.h>

typedef short bf16x8 __attribute__((ext_vector_type(8)));
typedef float f32x4 __attribute__((ext_vector_type(4)));

__device__ __forceinline__ int cvt2(float lo, float hi) {
    int r;
    asm("v_cvt_pk_bf16_f32 %0, %1, %2" : "=v"(r) : "v"(lo), "v"(hi));
    return r;
}

#define BAR() do {                                                        \
        asm volatile("s_waitcnt lgkmcnt(0)" ::: "memory");                \
        __builtin_amdgcn_s_barrier();                                     \
        __builtin_amdgcn_sched_barrier(0);                                \
    } while (0)

// ---------------------------------------------------------------------------
// Gates GEMM, split-K x2 (R10 block structure, K-halved). grid 512:
// b = tile(0..63) + 64*rgq(0..3) + 256*ks(0..1) — all 8 blocks of a tile
// share b%8 -> same XCD -> W re-reads are L2 hits; ks halves read DISJOINT
// K-ranges (no HBM duplication). Per-block K-loop schedule is byte-for-byte
// R10 (2-deep prefetch, double-buffered LDS, lgkm-only barriers), just 8
// steps from kt0 = ks*8. Epilogue stores raw gate partials to gbuf[ks][gate]
// (disjoint buffers — no atomics, no zero-init). GRU math moves to gru_k.
__global__ __launch_bounds__(256, 2) void gates_k(
    const float* __restrict__ x, const float* __restrict__ h1,
    const float* __restrict__ w_ih, const float* __restrict__ w_hh,
    float* __restrict__ gbuf,
    float* __restrict__ zf1p, float* __restrict__ zout)
{
    __shared__ short As[2][64 * 64];    // 16 KB: meta-rows 0..31 = x, 32..63 = h1
    __shared__ short Ws[2][96 * 64];    // 24 KB: meta-row g*16+jr, gates 0..5
    const int tid  = threadIdx.x;
    const int lane = tid & 63;
    const int wv   = tid >> 6;
    const int b    = blockIdx.x;

    // zero split-K atomic targets for fc1/fc3 (blocks 0..255 only)
    if (b < 256) {
        if (tid < 128) { f32x4 z = {}; *(f32x4*)(zf1p + b * 512 + tid * 4) = z; }
        if (tid < 32)  { f32x4 z = {}; *(f32x4*)(zout + b * 128 + tid * 4) = z; }
    }

    const int tile = b & 63;
    const int rgq  = (b >> 6) & 3;        // 0..3
    const int ks   = b >> 8;              // 0..1
    const int c0   = tile * 16;
    const int row0 = rgq * 32;
    const int kt0  = ks * 8;
    const int r0 = tid >> 3, kc = tid & 7;

    // A staging: 2 meta-rows/thread (x row, h1 row)
    const float* aP[2] = { x  + (row0 + r0) * 1024 + kc * 8,
                           h1 + (row0 + r0) * 1024 + kc * 8 };
    const int saI[2] = { (r0 * 64 + kc * 8) ^ ((r0 & 7) << 3),
                         ((r0 + 32) * 64 + kc * 8) ^ ((r0 & 7) << 3) };
    // W staging: 3 meta-rows/thread
    const float* wP[3];
    int swI[3];
    #pragma unroll
    for (int i = 0; i < 3; ++i) {
        int mw = r0 + 32 * i;                         // 0..95
        int g = mw >> 4;                              // gate 0..5
        const float* src = (g < 3) ? w_ih : w_hh;
        wP[i] = src + ((g % 3) * 1024 + c0 + (mw & 15)) * 1024 + kc * 8;
        swI[i] = (mw * 64 + kc * 8) ^ ((mw & 7) << 3);
    }

    f32x4 A[2][2][2], W[2][3][2];
    f32x4 acc[3] = {};

    const int rowg = wv & 1;              // 16-row group within the 32 rows
    const int hsel = wv >> 1;             // 0: gates 0-2 (i_*), 1: gates 3-5 (h_*)
    const int gbase = hsel * 3;

#define G_ISSUE(kt, s) do {                                               \
        _Pragma("unroll")                                                 \
        for (int i = 0; i < 2; ++i) {                                     \
            A[s][i][0] = *(const f32x4*)(aP[i] + (kt) * 64);              \
            A[s][i][1] = *(const f32x4*)(aP[i] + (kt) * 64 + 4);          \
        }                                                                 \
        _Pragma("unroll")                                                 \
        for (int i = 0; i < 3; ++i) {                                     \
            W[s][i][0] = *(const f32x4*)(wP[i] + (kt) * 64);              \
            W[s][i][1] = *(const f32x4*)(wP[i] + (kt) * 64 + 4);          \
        }                                                                 \
    } while (0)

#define G_STAGE(s, bb) do {                                               \
        _Pragma("unroll")                                                 \
        for (int i = 0; i < 2; ++i) {                                     \
            int4 p;                                                       \
            p.x = cvt2(A[s][i][0][0], A[s][i][0][1]);                     \
            p.y = cvt2(A[s][i][0][2], A[s][i][0][3]);                     \
            p.z = cvt2(A[s][i][1][0], A[s][i][1][1]);                     \
            p.w = cvt2(A[s][i][1][2], A[s][i][1][3]);                     \
            *(int4*)&As[bb][saI[i]] = p;                                  \
        }                                                                 \
        _Pragma("unroll")                                                 \
        for (int i = 0; i < 3; ++i) {                                     \
            int4 q;                                                       \
            q.x = cvt2(W[s][i][0][0], W[s][i][0][1]);                     \
            q.y = cvt2(W[s][i][0][2], W[s][i][0][3]);                     \
            q.z = cvt2(W[s][i][1][0], W[s][i][1][1]);                     \
            q.w = cvt2(W[s][i][1][2], W[s][i][1][3]);                     \
            *(int4*)&Ws[bb][swI[i]] = q;                                  \
        }                                                                 \
    } while (0)

#define G_COMPUTE(bb) do {                                                \
        _Pragma("unroll")                                                 \
        for (int kk = 0; kk < 64; kk += 32) {                             \
            const int kw = kk + 8 * (lane >> 4);                          \
            const int ma = hsel * 32 + rowg * 16 + (lane & 15);           \
            bf16x8 af = *(const bf16x8*)&As[bb][(ma * 64 + kw) ^ ((ma & 7) << 3)]; \
            _Pragma("unroll")                                             \
            for (int gg = 0; gg < 3; ++gg) {                              \
                int br = (gbase + gg) * 16 + (lane & 15);                 \
                bf16x8 bw = *(const bf16x8*)&Ws[bb][(br * 64 + kw) ^ ((br & 7) << 3)]; \
                acc[gg] = __builtin_amdgcn_mfma_f32_16x16x32_bf16(        \
                    af, bw, acc[gg], 0, 0, 0);                            \
            }                                                             \
        }                                                                 \
    } while (0)

    G_ISSUE(kt0 + 0, 0); G_ISSUE(kt0 + 1, 1);
    #pragma unroll 1
    for (int kt2 = 0; kt2 < 4; ++kt2) {
        const int kt = kt0 + 2 * kt2;
        G_STAGE(0, 0); if (kt + 2 < kt0 + 8) G_ISSUE(kt + 2, 0); BAR(); G_COMPUTE(0);
        G_STAGE(1, 1); if (kt + 3 < kt0 + 8) G_ISSUE(kt + 3, 1); BAR(); G_COMPUTE(1);
    }
#undef G_ISSUE
#undef G_STAGE
#undef G_COMPUTE

    // ---- epilogue: store raw gate partials (coalesced 16-col rows) ----
    const int j = c0 + (lane & 15);
    const int rbase = row0 + rowg * 16 + (lane >> 4) * 4;
    float* gb = gbuf + ks * 6 * 131072;
    #pragma unroll
    for (int gg = 0; gg < 3; ++gg) {
        float* gp = gb + (gbase + gg) * 131072;
        #pragma unroll
        for (int r = 0; r < 4; ++r)
            gp[(rbase + r) * 1024 + j] = acc[gg][r];
    }
}

// ---------------------------------------------------------------------------
// GRU elementwise: sums the two split-K gate partials, applies biases and
// GRU math, writes h1' (f32, d_out) and res = h1' + x (f32, ws).
__global__ __launch_bounds__(256) void gru_k(
    const float* __restrict__ gbuf, const float* __restrict__ x,
    const float* __restrict__ h1,
    const float* __restrict__ b_ih, const float* __restrict__ b_hh,
    float* __restrict__ h1p, float* __restrict__ res)
{
    int id = blockIdx.x * 256 + threadIdx.x;   // 0..131071
    int j = id & 1023;
    float g_[6];
    #pragma unroll
    for (int gi = 0; gi < 6; ++gi)
        g_[gi] = gbuf[gi * 131072 + id] + gbuf[(6 + gi) * 131072 + id];
    float ir  = g_[0] + b_ih[j];
    float iz  = g_[1] + b_ih[1024 + j];
    float inn = g_[2] + b_ih[2048 + j];
    float hr  = g_[3] + b_hh[j];
    float hz  = g_[4] + b_hh[1024 + j];
    float hn  = g_[5] + b_hh[2048 + j];
    float rr = 1.0f / (1.0f + __expf(-(ir + hr)));
    float zz = 1.0f / (1.0f + __expf(-(iz + hz)));
    float nn = tanhf(inn + rr * hn);
    float h1v = h1[id];
    float hp  = (1.0f - zz) * nn + zz * h1v;
    h1p[id] = hp;
    res[id] = hp + x[id];
}

// ---------------------------------------------------------------------------
// Generic tiled GEMM (fc1 / fc3): out rows [rg*64,+64) cols [c0,+NT)
// (+)= act[128][1024] @ wgt[N][1024]^T ; split-K via ksbits + atomics.
// (byte-for-byte the round-10 version — known good)
template<int NT, bool ATOMIC, bool RELUA>
__global__ __launch_bounds__(256, 2) void gemm_k(
    const float* __restrict__ act, const float* __restrict__ wgt,
    const float* __restrict__ bias,
    float* __restrict__ out, int ldo, int nkt, int ksbits)
{
    constexpr int CT = NT / 16;
    __shared__ short As[2][64 * 64];
    __shared__ short Ws[2][NT * 64];

    const int tid  = threadIdx.x;
    const int lane = tid & 63;
    const int wv   = tid >> 6;

    const int ks   = blockIdx.x & ((1 << ksbits) - 1);
    const int rest = blockIdx.x >> ksbits;
    const int rg   = rest & 1;
    const int tile = rest >> 1;
    const int c0   = tile * NT;
    const int row0 = rg * 64;
    const int kt0  = ks * nkt;

    const int r0 = tid >> 3, kc = tid & 7;
    const float* aP = act + (row0 + r0) * 1024 + kt0 * 64 + kc * 8;
    const float* wP = wgt + (c0 + r0) * 1024 + kt0 * 64 + kc * 8;
    const bool wAct = (tid < NT * 8);

    const int saI0 = (r0 * 64 + kc * 8) ^ ((r0 & 7) << 3);
    const int saI1 = ((r0 + 32) * 64 + kc * 8) ^ ((r0 & 7) << 3);

    f32x4 A[4][4], W[4][2];
    f32x4 acc[CT] = {};

#define ISSUE(kt, s) do {                                                 \
        A[s][0] = *(const f32x4*)(aP + (kt) * 64);                        \
        A[s][1] = *(const f32x4*)(aP + (kt) * 64 + 4);                    \
        A[s][2] = *(const f32x4*)(aP + (kt) * 64 + 32768);                \
        A[s][3] = *(const f32x4*)(aP + (kt) * 64 + 32772);                \
        if (wAct) {                                                       \
            W[s][0] = *(const f32x4*)(wP + (kt) * 64);                    \
            W[s][1] = *(const f32x4*)(wP + (kt) * 64 + 4);                \
        }                                                                 \
    } while (0)

#define RL(v) (RELUA ? fmaxf((v), 0.0f) : (v))

#define STAGE(s, b) do {                                                  \
        int4 p0, p1;                                                      \
        p0.x = cvt2(RL(A[s][0][0]), RL(A[s][0][1]));                      \
        p0.y = cvt2(RL(A[s][0][2]), RL(A[s][0][3]));                      \
        p0.z = cvt2(RL(A[s][1][0]), RL(A[s][1][1]));                      \
        p0.w = cvt2(RL(A[s][1][2]), RL(A[s][1][3]));                      \
        p1.x = cvt2(RL(A[s][2][0]), RL(A[s][2][1]));                      \
        p1.y = cvt2(RL(A[s][2][2]), RL(A[s][2][3]));                      \
        p1.z = cvt2(RL(A[s][3][0]), RL(A[s][3][1]));                      \
        p1.w = cvt2(RL(A[s][3][2]), RL(A[s][3][3]));                      \
        *(int4*)&As[b][saI0] = p0;                                        \
        *(int4*)&As[b][saI1] = p1;                                        \
        if (wAct) {                                                       \
            int4 q;                                                       \
            q.x = cvt2(W[s][0][0], W[s][0][1]);                           \
            q.y = cvt2(W[s][0][2], W[s][0][3]);                           \
            q.z = cvt2(W[s][1][0], W[s][1][1]);                           \
            q.w = cvt2(W[s][1][2], W[s][1][3]);                           \
            *(int4*)&Ws[b][saI0] = q;                                     \
        }                                                                 \
    } while (0)

#define COMPUTE(b) do {                                                   \
        _Pragma("unroll")                                                 \
        for (int kk = 0; kk < 64; kk += 32) {                             \
            const int kw = kk + 8 * (lane >> 4);                          \
            const int ar = wv * 16 + (lane & 15);                         \
            bf16x8 af = *(const bf16x8*)&As[b][(ar * 64 + kw) ^ ((ar & 7) << 3)]; \
            bf16x8 bw[CT];                                                \
            _Pragma("unroll")                                             \
            for (int ct = 0; ct < CT; ++ct) {                             \
                int br = ct * 16 + (lane & 15);                           \
                bw[ct] = *(const bf16x8*)&Ws[b][(br * 64 + kw) ^ ((br & 7) << 3)]; \
            }                                                             \
            _Pragma("unroll")                                             \
            for (int ct = 0; ct < CT; ++ct)                               \
                acc[ct] = __builtin_amdgcn_mfma_f32_16x16x32_bf16(        \
                    af, bw[ct], acc[ct], 0, 0, 0);                        \
        }                                                                 \
    } while (0)

    ISSUE(0, 0); ISSUE(1, 1); ISSUE(2, 2); ISSUE(3, 3);

    #pragma unroll 1
    for (int g = 0; g < nkt / 4; ++g) {
        const int kt = 4 * g;
        STAGE(0, 0); if (kt + 4 < nkt) ISSUE(kt + 4, 0); BAR(); COMPUTE(0);
        STAGE(1, 1); if (kt + 5 < nkt) ISSUE(kt + 5, 1); BAR(); COMPUTE(1);
        STAGE(2, 0); if (kt + 6 < nkt) ISSUE(kt + 6, 2); BAR(); COMPUTE(0);
        STAGE(3, 1); if (kt + 7 < nkt) ISSUE(kt + 7, 3); BAR(); COMPUTE(1);
    }

#undef ISSUE
#undef RL
#undef STAGE
#undef COMPUTE

    #pragma unroll
    for (int ct = 0; ct < CT; ++ct) {
        int col = c0 + ct * 16 + (lane & 15);
        float bv = (bias && ks == 0) ? bias[col] : 0.0f;
        #pragma unroll
        for (int r = 0; r < 4; ++r) {
            int row = row0 + wv * 16 + (lane >> 4) * 4 + r;
            float v = acc[ct][r] + bv;
            if (ATOMIC) unsafeAtomicAdd(&out[row * ldo + col], v);
            else        out[row * ldo + col] = v;
        }
    }
}

extern "C" void kernel_launch(void* const* d_in, const int* in_sizes, int n_in,
                              void* d_out, int out_size, void* d_ws, size_t ws_size,
                              hipStream_t stream)
{
    const float* x     = (const float*)d_in[0];
    const float* h1    = (const float*)d_in[1];
    const float* w_ih  = (const float*)d_in[2];
    const float* w_hh  = (const float*)d_in[3];
    const float* b_ih  = (const float*)d_in[4];
    const float* b_hh  = (const float*)d_in[5];
    const float* w_fc1 = (const float*)d_in[6];
    const float* b_fc1 = (const float*)d_in[7];
    const float* w_fc3 = (const float*)d_in[8];
    const float* b_fc3 = (const float*)d_in[9];

    float* out = (float*)d_out;          // [128][256]
    float* h1p = out + 128 * 256;        // [128][1024]

    float* ws   = (float*)d_ws;
    float* res  = ws;                    // [128][1024] h1' + x
    float* f1p  = ws + 128 * 1024;       // [128][1024] fc1 pre-activation
    float* gbuf = ws + 256 * 1024;       // [2][6][128][1024] gate partials, 6 MB

    // gates split-K x2 -> gbuf; blocks 0..255 also zero f1p and out
    gates_k<<<512, 256, 0, stream>>>(x, h1, w_ih, w_hh, gbuf, f1p, out);
    // GRU elementwise: sum partials + biases -> h1p (d_out), res (ws)
    gru_k<<<512, 256, 0, stream>>>(gbuf, x, h1, b_ih, b_hh, h1p, res);
    // f1p += res @ w_fc1^T + b_fc1   (64 tiles x 2 rg x 4 ks = 512 blocks)
    gemm_k<16, true, false><<<512, 256, 0, stream>>>(
        res, w_fc1, b_fc1, f1p, 1024, 4, 2);
    // out += relu(f1p) @ w_fc3^T + b_fc3  (16 x 2 x 4 = 128 blocks)
    gemm_k<16, true, true><<<128, 256, 0, stream>>>(
        f1p, w_fc3, b_fc3, out, 256, 4, 2);
}

// Round 15
// 25.576 us; speedup vs baseline: 1.0431x; 1.0431x over previous
//
#include <hip/hip_runtime.h>
#include <math.h>

typedef short bf16x8 __attribute__((ext_vector_type(8)));
typedef float f32x4 __attribute__((ext_vector_type(4)));

__device__ __forceinline__ int cvt2(float lo, float hi) {
    int r;
    asm("v_cvt_pk_bf16_f32 %0, %1, %2" : "=v"(r) : "v"(lo), "v"(hi));
    return r;
}

#define BAR() do {                                                        \
        asm volatile("s_waitcnt lgkmcnt(0)" ::: "memory");                \
        __builtin_amdgcn_s_barrier();                                     \
        __builtin_amdgcn_sched_barrier(0);                                \
    } while (0)

// ---------------------------------------------------------------------------
// FINAL (R10 pin — best measured: 24.8us, reproduced 25.45us).
// Fused gates GEMM + GRU. grid 256 (ALL CUs): block = (tile 0..63, rgq 0..3)
// -> 32 rows x 16 cols. The four rgq of a tile share b%8 (64%8==0) -> same
// XCD -> W re-reads are L2 hits. Wave = (rowg = wv&1, gate-trio = (wv>>1)*3):
// per kk each wave reads 1 A-frag + 3 W-frags. GRU epilogue exchanges the
// h-gate accumulators through 6 KB of LDS. K-loop schedule: 2-deep register
// prefetch, 16 steps, double-buffered LDS, lgkm-only barriers (globals stay
// in flight across barriers).
// Ledger of failed perturbations (do not retry): helper-block traffic
// (R6/R7), 4-deep W prefetch (R8), persistent-kernel grid sync (R5 acquire-
// poll L2-invalidate storm; R9 same-line RMW serialization ~27us/barrier),
// A-direct fragment loads (R11, scatter), bf16 res (R12), gates split-K (R14).
__global__ __launch_bounds__(256, 2) void gates_k(
    const float* __restrict__ x, const float* __restrict__ h1,
    const float* __restrict__ w_ih, const float* __restrict__ w_hh,
    const float* __restrict__ b_ih, const float* __restrict__ b_hh,
    float* __restrict__ h1p, float* __restrict__ res,
    float* __restrict__ zf1p, float* __restrict__ zout)
{
    __shared__ short As[2][64 * 64];    // 16 KB: meta-rows 0..31 = x, 32..63 = h1
    __shared__ short Ws[2][96 * 64];    // 24 KB: meta-row g*16+jr, gates 0..5
    const int tid  = threadIdx.x;
    const int lane = tid & 63;
    const int wv   = tid >> 6;
    const int b    = blockIdx.x;

    // zero split-K atomic targets (spread over all 256 blocks)
    if (tid < 128) { f32x4 z = {}; *(f32x4*)(zf1p + b * 512 + tid * 4) = z; }
    if (tid < 32)  { f32x4 z = {}; *(f32x4*)(zout + b * 128 + tid * 4) = z; }

    const int tile = b & 63;
    const int rgq  = b >> 6;              // 0..3
    const int c0   = tile * 16;
    const int row0 = rgq * 32;
    const int r0 = tid >> 3, kc = tid & 7;

    // A staging: 2 meta-rows/thread (x row, h1 row)
    const float* aP[2] = { x  + (row0 + r0) * 1024 + kc * 8,
                           h1 + (row0 + r0) * 1024 + kc * 8 };
    const int saI[2] = { (r0 * 64 + kc * 8) ^ ((r0 & 7) << 3),
                         ((r0 + 32) * 64 + kc * 8) ^ ((r0 & 7) << 3) };
    // W staging: 3 meta-rows/thread
    const float* wP[3];
    int swI[3];
    #pragma unroll
    for (int i = 0; i < 3; ++i) {
        int mw = r0 + 32 * i;                         // 0..95
        int g = mw >> 4;                              // gate 0..5
        const float* src = (g < 3) ? w_ih : w_hh;
        wP[i] = src + ((g % 3) * 1024 + c0 + (mw & 15)) * 1024 + kc * 8;
        swI[i] = (mw * 64 + kc * 8) ^ ((mw & 7) << 3);
    }

    f32x4 A[2][2][2], W[2][3][2];
    f32x4 acc[3] = {};

    const int rowg = wv & 1;              // 16-row group within the 32 rows
    const int hsel = wv >> 1;             // 0: gates 0-2 (i_*), 1: gates 3-5 (h_*)
    const int gbase = hsel * 3;

#define G_ISSUE(kt, s) do {                                               \
        _Pragma("unroll")                                                 \
        for (int i = 0; i < 2; ++i) {                                     \
            A[s][i][0] = *(const f32x4*)(aP[i] + (kt) * 64);              \
            A[s][i][1] = *(const f32x4*)(aP[i] + (kt) * 64 + 4);          \
        }                                                                 \
        _Pragma("unroll")                                                 \
        for (int i = 0; i < 3; ++i) {                                     \
            W[s][i][0] = *(const f32x4*)(wP[i] + (kt) * 64);              \
            W[s][i][1] = *(const f32x4*)(wP[i] + (kt) * 64 + 4);          \
        }                                                                 \
    } while (0)

#define G_STAGE(s, bb) do {                                               \
        _Pragma("unroll")                                                 \
        for (int i = 0; i < 2; ++i) {                                     \
            int4 p;                                                       \
            p.x = cvt2(A[s][i][0][0], A[s][i][0][1]);                     \
            p.y = cvt2(A[s][i][0][2], A[s][i][0][3]);                     \
            p.z = cvt2(A[s][i][1][0], A[s][i][1][1]);                     \
            p.w = cvt2(A[s][i][1][2], A[s][i][1][3]);                     \
            *(int4*)&As[bb][saI[i]] = p;                                  \
        }                                                                 \
        _Pragma("unroll")                                                 \
        for (int i = 0; i < 3; ++i) {                                     \
            int4 q;                                                       \
            q.x = cvt2(W[s][i][0][0], W[s][i][0][1]);                     \
            q.y = cvt2(W[s][i][0][2], W[s][i][0][3]);                     \
            q.z = cvt2(W[s][i][1][0], W[s][i][1][1]);                     \
            q.w = cvt2(W[s][i][1][2], W[s][i][1][3]);                     \
            *(int4*)&Ws[bb][swI[i]] = q;                                  \
        }                                                                 \
    } while (0)

#define G_COMPUTE(bb) do {                                                \
        _Pragma("unroll")                                                 \
        for (int kk = 0; kk < 64; kk += 32) {                             \
            const int kw = kk + 8 * (lane >> 4);                          \
            const int ma = hsel * 32 + rowg * 16 + (lane & 15);           \
            bf16x8 af = *(const bf16x8*)&As[bb][(ma * 64 + kw) ^ ((ma & 7) << 3)]; \
            _Pragma("unroll")                                             \
            for (int gg = 0; gg < 3; ++gg) {                              \
                int br = (gbase + gg) * 16 + (lane & 15);                 \
                bf16x8 bw = *(const bf16x8*)&Ws[bb][(br * 64 + kw) ^ ((br & 7) << 3)]; \
                acc[gg] = __builtin_amdgcn_mfma_f32_16x16x32_bf16(        \
                    af, bw, acc[gg], 0, 0, 0);                            \
            }                                                             \
        }                                                                 \
    } while (0)

    G_ISSUE(0, 0); G_ISSUE(1, 1);
    #pragma unroll 1
    for (int kt2 = 0; kt2 < 8; ++kt2) {
        const int kt = 2 * kt2;
        G_STAGE(0, 0); if (kt + 2 < 16) G_ISSUE(kt + 2, 0); BAR(); G_COMPUTE(0);
        G_STAGE(1, 1); if (kt + 3 < 16) G_ISSUE(kt + 3, 1); BAR(); G_COMPUTE(1);
    }
#undef G_ISSUE
#undef G_STAGE
#undef G_COMPUTE

    // ---- GRU epilogue: waves 2/3 export h-gates via LDS; waves 0/1 combine.
    // As[0] is free: its last reads (kt=14, buffer 0) were barriered before
    // the final COMPUTE(1). 6 KB used of 16 KB.
    float* xch = (float*)&As[0][0];
    if (hsel) {
        #pragma unroll
        for (int gg = 0; gg < 3; ++gg)
            #pragma unroll
            for (int r = 0; r < 4; ++r)
                xch[(rowg * 3 + gg) * 256 + ((lane >> 4) * 4 + r) * 16 + (lane & 15)]
                    = acc[gg][r];
    }
    BAR();
    if (!hsel) {
        const int j = c0 + (lane & 15);
        const float bir = b_ih[j], biz = b_ih[1024 + j], bin = b_ih[2048 + j];
        const float bhr = b_hh[j], bhz = b_hh[1024 + j], bhn = b_hh[2048 + j];
        const int rbase = row0 + rowg * 16 + (lane >> 4) * 4;
        #pragma unroll
        for (int r = 0; r < 4; ++r) {
            const int row = rbase + r;
            const int xb  = rowg * 3 * 256 + ((lane >> 4) * 4 + r) * 16 + (lane & 15);
            float ir  = acc[0][r] + bir, iz = acc[1][r] + biz, inn = acc[2][r] + bin;
            float hr  = xch[xb] + bhr, hz = xch[xb + 256] + bhz, hn = xch[xb + 512] + bhn;
            float rr = 1.0f / (1.0f + __expf(-(ir + hr)));
            float zz = 1.0f / (1.0f + __expf(-(iz + hz)));
            float nn = tanhf(inn + rr * hn);
            float h1v = h1[row * 1024 + j];
            float hp  = (1.0f - zz) * nn + zz * h1v;
            h1p[row * 1024 + j] = hp;
            res[row * 1024 + j] = hp + x[row * 1024 + j];
        }
    }
}

// ---------------------------------------------------------------------------
// Generic tiled GEMM (fc1 / fc3): out rows [rg*64,+64) cols [c0,+NT)
// (+)= act[128][1024] @ wgt[N][1024]^T ; split-K via ksbits + atomics.
template<int NT, bool ATOMIC, bool RELUA>
__global__ __launch_bounds__(256, 2) void gemm_k(
    const float* __restrict__ act, const float* __restrict__ wgt,
    const float* __restrict__ bias,
    float* __restrict__ out, int ldo, int nkt, int ksbits)
{
    constexpr int CT = NT / 16;
    __shared__ short As[2][64 * 64];
    __shared__ short Ws[2][NT * 64];

    const int tid  = threadIdx.x;
    const int lane = tid & 63;
    const int wv   = tid >> 6;

    const int ks   = blockIdx.x & ((1 << ksbits) - 1);
    const int rest = blockIdx.x >> ksbits;
    const int rg   = rest & 1;
    const int tile = rest >> 1;
    const int c0   = tile * NT;
    const int row0 = rg * 64;
    const int kt0  = ks * nkt;

    const int r0 = tid >> 3, kc = tid & 7;
    const float* aP = act + (row0 + r0) * 1024 + kt0 * 64 + kc * 8;
    const float* wP = wgt + (c0 + r0) * 1024 + kt0 * 64 + kc * 8;
    const bool wAct = (tid < NT * 8);

    const int saI0 = (r0 * 64 + kc * 8) ^ ((r0 & 7) << 3);
    const int saI1 = ((r0 + 32) * 64 + kc * 8) ^ ((r0 & 7) << 3);

    f32x4 A[4][4], W[4][2];
    f32x4 acc[CT] = {};

#define ISSUE(kt, s) do {                                                 \
        A[s][0] = *(const f32x4*)(aP + (kt) * 64);                        \
        A[s][1] = *(const f32x4*)(aP + (kt) * 64 + 4);                    \
        A[s][2] = *(const f32x4*)(aP + (kt) * 64 + 32768);                \
        A[s][3] = *(const f32x4*)(aP + (kt) * 64 + 32772);                \
        if (wAct) {                                                       \
            W[s][0] = *(const f32x4*)(wP + (kt) * 64);                    \
            W[s][1] = *(const f32x4*)(wP + (kt) * 64 + 4);                \
        }                                                                 \
    } while (0)

#define RL(v) (RELUA ? fmaxf((v), 0.0f) : (v))

#define STAGE(s, b) do {                                                  \
        int4 p0, p1;                                                      \
        p0.x = cvt2(RL(A[s][0][0]), RL(A[s][0][1]));                      \
        p0.y = cvt2(RL(A[s][0][2]), RL(A[s][0][3]));                      \
        p0.z = cvt2(RL(A[s][1][0]), RL(A[s][1][1]));                      \
        p0.w = cvt2(RL(A[s][1][2]), RL(A[s][1][3]));                      \
        p1.x = cvt2(RL(A[s][2][0]), RL(A[s][2][1]));                      \
        p1.y = cvt2(RL(A[s][2][2]), RL(A[s][2][3]));                      \
        p1.z = cvt2(RL(A[s][3][0]), RL(A[s][3][1]));                      \
        p1.w = cvt2(RL(A[s][3][2]), RL(A[s][3][3]));                      \
        *(int4*)&As[b][saI0] = p0;                                        \
        *(int4*)&As[b][saI1] = p1;                                        \
        if (wAct) {                                                       \
            int4 q;                                                       \
            q.x = cvt2(W[s][0][0], W[s][0][1]);                           \
            q.y = cvt2(W[s][0][2], W[s][0][3]);                           \
            q.z = cvt2(W[s][1][0], W[s][1][1]);                           \
            q.w = cvt2(W[s][1][2], W[s][1][3]);                           \
            *(int4*)&Ws[b][saI0] = q;                                     \
        }                                                                 \
    } while (0)

#define COMPUTE(b) do {                                                   \
        _Pragma("unroll")                                                 \
        for (int kk = 0; kk < 64; kk += 32) {                             \
            const int kw = kk + 8 * (lane >> 4);                          \
            const int ar = wv * 16 + (lane & 15);                         \
            bf16x8 af = *(const bf16x8*)&As[b][(ar * 64 + kw) ^ ((ar & 7) << 3)]; \
            bf16x8 bw[CT];                                                \
            _Pragma("unroll")                                             \
            for (int ct = 0; ct < CT; ++ct) {                             \
                int br = ct * 16 + (lane & 15);                           \
                bw[ct] = *(const bf16x8*)&Ws[b][(br * 64 + kw) ^ ((br & 7) << 3)]; \
            }                                                             \
            _Pragma("unroll")                                             \
            for (int ct = 0; ct < CT; ++ct)                               \
                acc[ct] = __builtin_amdgcn_mfma_f32_16x16x32_bf16(        \
                    af, bw[ct], acc[ct], 0, 0, 0);                        \
        }                                                                 \
    } while (0)

    ISSUE(0, 0); ISSUE(1, 1); ISSUE(2, 2); ISSUE(3, 3);

    #pragma unroll 1
    for (int g = 0; g < nkt / 4; ++g) {
        const int kt = 4 * g;
        STAGE(0, 0); if (kt + 4 < nkt) ISSUE(kt + 4, 0); BAR(); COMPUTE(0);
        STAGE(1, 1); if (kt + 5 < nkt) ISSUE(kt + 5, 1); BAR(); COMPUTE(1);
        STAGE(2, 0); if (kt + 6 < nkt) ISSUE(kt + 6, 2); BAR(); COMPUTE(0);
        STAGE(3, 1); if (kt + 7 < nkt) ISSUE(kt + 7, 3); BAR(); COMPUTE(1);
    }

#undef ISSUE
#undef RL
#undef STAGE
#undef COMPUTE

    #pragma unroll
    for (int ct = 0; ct < CT; ++ct) {
        int col = c0 + ct * 16 + (lane & 15);
        float bv = (bias && ks == 0) ? bias[col] : 0.0f;
        #pragma unroll
        for (int r = 0; r < 4; ++r) {
            int row = row0 + wv * 16 + (lane >> 4) * 4 + r;
            float v = acc[ct][r] + bv;
            if (ATOMIC) unsafeAtomicAdd(&out[row * ldo + col], v);
            else        out[row * ldo + col] = v;
        }
    }
}

extern "C" void kernel_launch(void* const* d_in, const int* in_sizes, int n_in,
                              void* d_out, int out_size, void* d_ws, size_t ws_size,
                              hipStream_t stream)
{
    const float* x     = (const float*)d_in[0];
    const float* h1    = (const float*)d_in[1];
    const float* w_ih  = (const float*)d_in[2];
    const float* w_hh  = (const float*)d_in[3];
    const float* b_ih  = (const float*)d_in[4];
    const float* b_hh  = (const float*)d_in[5];
    const float* w_fc1 = (const float*)d_in[6];
    const float* b_fc1 = (const float*)d_in[7];
    const float* w_fc3 = (const float*)d_in[8];
    const float* b_fc3 = (const float*)d_in[9];

    float* out = (float*)d_out;          // [128][256]
    float* h1p = out + 128 * 256;        // [128][1024]

    float* ws  = (float*)d_ws;
    float* res = ws;                     // [128][1024] h1' + x
    float* f1p = ws + 128 * 1024;        // [128][1024] fc1 pre-activation

    // fused gates GEMM + GRU -> h1p (d_out) and res; zeroes f1p and out
    gates_k<<<256, 256, 0, stream>>>(x, h1, w_ih, w_hh, b_ih, b_hh,
                                     h1p, res, f1p, out);
    // f1p += res @ w_fc1^T + b_fc1   (64 tiles x 2 rg x 4 ks = 512 blocks, 4 steps)
    gemm_k<16, true, false><<<512, 256, 0, stream>>>(
        res, w_fc1, b_fc1, f1p, 1024, 4, 2);
    // out += relu(f1p) @ w_fc3^T + b_fc3  (16 x 2 x 4 = 128 blocks, 4 steps)
    gemm_k<16, true, true><<<128, 256, 0, stream>>>(
        f1p, w_fc3, b_fc3, out, 256, 4, 2);
}